// Round 1
// baseline (832.308 us; speedup 1.0000x reference)
//
#include <hip/hip_runtime.h>
#include <stdint.h>

// ---------- problem constants ----------
#define B_DIM 2
#define T_DIM 4096
#define C_DIM 512
#define H_DIM 8
#define D_DIM 64
#define M_DIM (B_DIM * T_DIM)   // 8192

typedef __attribute__((ext_vector_type(8))) short bf16x8;   // MFMA A/B frag (8 bf16)
typedef __attribute__((ext_vector_type(4))) float f32x4;    // MFMA C/D frag
typedef __attribute__((ext_vector_type(4))) short short4v;  // 8B vector

__device__ inline unsigned short f2bf(float f) {
    union { float f; uint32_t u; } v; v.f = f;
    uint32_t r = v.u + 0x7fffu + ((v.u >> 16) & 1u);   // RNE
    return (unsigned short)(r >> 16);
}

// ---------- f32 -> bf16 conversion ----------
__global__ __launch_bounds__(256) void cvt_kernel(const float* __restrict__ in,
                                                  unsigned short* __restrict__ out, int n) {
    int i = (blockIdx.x * 256 + threadIdx.x) * 4;
    if (i >= n) return;
    float4 v = *(const float4*)(in + i);
    short4v o;
    o[0] = (short)f2bf(v.x);
    o[1] = (short)f2bf(v.y);
    o[2] = (short)f2bf(v.z);
    o[3] = (short)f2bf(v.w);
    *(short4v*)(out + i) = o;
}

// ---------- GEMM: Y[m][n] = sum_k A[m][k] * W[n][k]  (y = A @ W^T) ----------
// A: [M][512] bf16 row-major.  W: [512][512] bf16 row-major.
// MODE 0: out = bf16, head-split [B][H][T][D]   (Q, K)
// MODE 2: out = bf16, head-split transposed [B][H][D][T]  (V^T)
// MODE 3: out = f32 row-major [M][512]          (final output)
template<int MODE>
__global__ __launch_bounds__(256) void gemm_bt(const unsigned short* __restrict__ A,
                                               const unsigned short* __restrict__ W,
                                               void* __restrict__ out) {
    const int wave = threadIdx.x >> 6;
    const int lane = threadIdx.x & 63;
    const int g    = lane >> 4;    // 0..3 (k-group)
    const int lr   = lane & 15;    // 0..15
    const int row0 = blockIdx.x * 64 + wave * 16;
    const int col0 = blockIdx.y * 64;

    f32x4 acc[4];
#pragma unroll
    for (int i = 0; i < 4; ++i) acc[i] = (f32x4){0.f, 0.f, 0.f, 0.f};

    const unsigned short* Arow = A + (size_t)(row0 + lr) * C_DIM;
#pragma unroll 4
    for (int kk = 0; kk < C_DIM; kk += 32) {
        bf16x8 a = *(const bf16x8*)(Arow + kk + g * 8);
#pragma unroll
        for (int nt = 0; nt < 4; ++nt) {
            const unsigned short* Wrow = W + (size_t)(col0 + nt * 16 + lr) * C_DIM;
            bf16x8 b = *(const bf16x8*)(Wrow + kk + g * 8);
            acc[nt] = __builtin_amdgcn_mfma_f32_16x16x32_bf16(a, b, acc[nt], 0, 0, 0);
        }
    }

#pragma unroll
    for (int nt = 0; nt < 4; ++nt) {
        const int n = col0 + nt * 16 + lr;
        if (MODE == 3) {
            float* O = (float*)out;
#pragma unroll
            for (int j = 0; j < 4; ++j) {
                int m = row0 + g * 4 + j;
                O[(size_t)m * C_DIM + n] = acc[nt][j];
            }
        } else {
            const int h = n >> 6, d = n & 63;
            unsigned short* O = (unsigned short*)out;
            if (MODE == 0) {
#pragma unroll
                for (int j = 0; j < 4; ++j) {
                    int m = row0 + g * 4 + j;
                    int b = m >> 12, t = m & (T_DIM - 1);
                    O[((size_t)(b * H_DIM + h) * T_DIM + t) * D_DIM + d] = f2bf(acc[nt][j]);
                }
            } else {  // MODE 2: V transposed [B][H][D][T]
                int m = row0 + g * 4;
                int b = m >> 12, t = m & (T_DIM - 1);
                short4v pack;
#pragma unroll
                for (int j = 0; j < 4; ++j) pack[j] = (short)f2bf(acc[nt][j]);
                *(short4v*)(O + ((size_t)(b * H_DIM + h) * D_DIM + d) * T_DIM + t) = pack;
            }
        }
    }
}

// ---------- causal flash attention ----------
// Q,K: [B*H][T][D] bf16.  Vt: [B*H][D][T] bf16.  attn out: [B*T][C] bf16 (merged heads).
// One wave owns a 16-row Q tile. Swapped QK^T: S^T = mfma(K, Q) so the S^T C-frag has
// col = q (lane&15) -> row stats via shfl_xor(16/32); O^T accumulated, A-operand = V^T.
__global__ __launch_bounds__(256) void attn_kernel(const unsigned short* __restrict__ Qh,
                                                   const unsigned short* __restrict__ Kh,
                                                   const unsigned short* __restrict__ Vt,
                                                   unsigned short* __restrict__ attn) {
    const int wid  = blockIdx.x * 4 + (threadIdx.x >> 6);
    const int lane = threadIdx.x & 63;
    const int g    = lane >> 4;
    const int lr   = lane & 15;
    const int bh   = wid >> 8;    // 0..15
    const int qt   = wid & 255;
    const int q0   = qt * 16;

    const unsigned short* Qp = Qh + (size_t)bh * T_DIM * D_DIM;
    const unsigned short* Kp = Kh + (size_t)bh * T_DIM * D_DIM;
    const unsigned short* Vp = Vt + (size_t)bh * D_DIM * T_DIM;

    // Q as B-operand: col = q0+lr, k = d
    const bf16x8 qf0 = *(const bf16x8*)(Qp + (size_t)(q0 + lr) * D_DIM + g * 8);
    const bf16x8 qf1 = *(const bf16x8*)(Qp + (size_t)(q0 + lr) * D_DIM + 32 + g * 8);

    f32x4 o[4];
#pragma unroll
    for (int i = 0; i < 4; ++i) o[i] = (f32x4){0.f, 0.f, 0.f, 0.f};
    float mrun = -INFINITY, lrun = 0.f;

    const int q  = q0 + lr;
    const int nb = (q0 + 47) >> 5;   // ceil((q0+16)/32)

    for (int kb = 0; kb < nb; ++kb) {
        const int kv0 = kb << 5;
        f32x4 s0 = (f32x4){0.f, 0.f, 0.f, 0.f};
        f32x4 s1 = (f32x4){0.f, 0.f, 0.f, 0.f};
        const unsigned short* K0 = Kp + (size_t)(kv0 + lr) * D_DIM;
        const unsigned short* K1 = Kp + (size_t)(kv0 + 16 + lr) * D_DIM;
        s0 = __builtin_amdgcn_mfma_f32_16x16x32_bf16(*(const bf16x8*)(K0 + g * 8),      qf0, s0, 0, 0, 0);
        s0 = __builtin_amdgcn_mfma_f32_16x16x32_bf16(*(const bf16x8*)(K0 + 32 + g * 8), qf1, s0, 0, 0, 0);
        s1 = __builtin_amdgcn_mfma_f32_16x16x32_bf16(*(const bf16x8*)(K1 + g * 8),      qf0, s1, 0, 0, 0);
        s1 = __builtin_amdgcn_mfma_f32_16x16x32_bf16(*(const bf16x8*)(K1 + 32 + g * 8), qf1, s1, 0, 0, 0);

        const bool maskblk = (kv0 + 31 > q0);
        float z[8];
#pragma unroll
        for (int j = 0; j < 4; ++j) {
            const int kva = kv0 + g * 4 + j;
            z[j]     = (maskblk && (kva      > q)) ? -INFINITY : s0[j] * 0.125f;
            z[4 + j] = (maskblk && (kva + 16 > q)) ? -INFINITY : s1[j] * 0.125f;
        }
        float mt = z[0];
#pragma unroll
        for (int j = 1; j < 8; ++j) mt = fmaxf(mt, z[j]);
        mt = fmaxf(mt, __shfl_xor(mt, 16));
        mt = fmaxf(mt, __shfl_xor(mt, 32));
        const float mnew  = fmaxf(mrun, mt);
        const float alpha = exp2f((mrun - mnew) * 1.44269504f);

        float psum = 0.f;
        bf16x8 pf;
#pragma unroll
        for (int j = 0; j < 8; ++j) {
            float p = exp2f((z[j] - mnew) * 1.44269504f);
            psum += p;
            pf[j] = (short)f2bf(p);
        }
        psum += __shfl_xor(psum, 16);
        psum += __shfl_xor(psum, 32);
        lrun = lrun * alpha + psum;
        mrun = mnew;
#pragma unroll
        for (int i = 0; i < 4; ++i) {
            o[i][0] *= alpha; o[i][1] *= alpha; o[i][2] *= alpha; o[i][3] *= alpha;
        }

        // PV: O^T += V^T * P^T  (custom-but-consistent k mapping on both operands)
#pragma unroll
        for (int d0 = 0; d0 < 4; ++d0) {
            const unsigned short* Vr = Vp + (size_t)(d0 * 16 + lr) * T_DIM + kv0 + g * 4;
            short4v vlo = *(const short4v*)(Vr);
            short4v vhi = *(const short4v*)(Vr + 16);
            bf16x8 vf;
            vf[0] = vlo[0]; vf[1] = vlo[1]; vf[2] = vlo[2]; vf[3] = vlo[3];
            vf[4] = vhi[0]; vf[5] = vhi[1]; vf[6] = vhi[2]; vf[7] = vhi[3];
            o[d0] = __builtin_amdgcn_mfma_f32_16x16x32_bf16(vf, pf, o[d0], 0, 0, 0);
        }
    }

    const float inv = 1.0f / lrun;
    const int b = bh >> 3, h = bh & 7;
    unsigned short* orow = attn + ((size_t)(b * T_DIM + q0 + lr)) * C_DIM + h * D_DIM;
#pragma unroll
    for (int d0 = 0; d0 < 4; ++d0)
#pragma unroll
        for (int j = 0; j < 4; ++j)
            orow[d0 * 16 + g * 4 + j] = f2bf(o[d0][j] * inv);
}

// ---------- launch ----------
extern "C" void kernel_launch(void* const* d_in, const int* in_sizes, int n_in,
                              void* d_out, int out_size, void* d_ws, size_t ws_size,
                              hipStream_t stream) {
    const float* x  = (const float*)d_in[0];
    const float* Wq = (const float*)d_in[1];
    const float* Wk = (const float*)d_in[2];
    const float* Wv = (const float*)d_in[3];
    const float* Wo = (const float*)d_in[4];

    char* ws = (char*)d_ws;
    // workspace layout (bytes)
    unsigned short* xb    = (unsigned short*)(ws + 0);         //  8 MB  x bf16 [8192][512]
    unsigned short* Wqb   = (unsigned short*)(ws + 8388608);   // 512 KB
    unsigned short* Wkb   = (unsigned short*)(ws + 8912896);
    unsigned short* Wvb   = (unsigned short*)(ws + 9437184);
    unsigned short* Wob   = (unsigned short*)(ws + 9961472);
    unsigned short* Qh    = (unsigned short*)(ws + 10485760);  //  8 MB [B][H][T][D]
    unsigned short* Kh    = (unsigned short*)(ws + 18874368);  //  8 MB
    unsigned short* Vt    = (unsigned short*)(ws + 27262976);  //  8 MB [B][H][D][T]
    unsigned short* attnb = (unsigned short*)(ws + 35651584);  //  8 MB [8192][512]

    const int nX = M_DIM * C_DIM;      // 4194304
    const int nW = C_DIM * C_DIM;      // 262144

    cvt_kernel<<<nX / 4 / 256, 256, 0, stream>>>(x, xb, nX);
    cvt_kernel<<<nW / 4 / 256, 256, 0, stream>>>(Wq, Wqb, nW);
    cvt_kernel<<<nW / 4 / 256, 256, 0, stream>>>(Wk, Wkb, nW);
    cvt_kernel<<<nW / 4 / 256, 256, 0, stream>>>(Wv, Wvb, nW);
    cvt_kernel<<<nW / 4 / 256, 256, 0, stream>>>(Wo, Wob, nW);

    dim3 ggrid(M_DIM / 64, C_DIM / 64);
    gemm_bt<0><<<ggrid, 256, 0, stream>>>(xb, Wqb, Qh);
    gemm_bt<0><<<ggrid, 256, 0, stream>>>(xb, Wkb, Kh);
    gemm_bt<2><<<ggrid, 256, 0, stream>>>(xb, Wvb, Vt);

    attn_kernel<<<(B_DIM * H_DIM * (T_DIM / 16)) / 4, 256, 0, stream>>>(Qh, Kh, Vt, attnb);

    gemm_bt<3><<<ggrid, 256, 0, stream>>>(attnb, Wob, d_out);
}

// Round 2
// 505.778 us; speedup vs baseline: 1.6456x; 1.6456x over previous
//
#include <hip/hip_runtime.h>
#include <stdint.h>

// ---------- problem constants ----------
#define B_DIM 2
#define T_DIM 4096
#define C_DIM 512
#define H_DIM 8
#define D_DIM 64
#define M_DIM (B_DIM * T_DIM)   // 8192

typedef __attribute__((ext_vector_type(8))) short bf16x8;   // MFMA A/B frag (8 bf16)
typedef __attribute__((ext_vector_type(4))) float f32x4;    // MFMA C/D frag
typedef __attribute__((ext_vector_type(4))) short short4v;  // 8B vector

__device__ inline unsigned short f2bf(float f) {
    union { float f; uint32_t u; } v; v.f = f;
    uint32_t r = v.u + 0x7fffu + ((v.u >> 16) & 1u);   // RNE
    return (unsigned short)(r >> 16);
}

// ---------- f32 -> bf16 conversion ----------
__global__ __launch_bounds__(256) void cvt_kernel(const float* __restrict__ in,
                                                  unsigned short* __restrict__ out, int n) {
    int i = (blockIdx.x * 256 + threadIdx.x) * 4;
    if (i >= n) return;
    float4 v = *(const float4*)(in + i);
    short4v o;
    o[0] = (short)f2bf(v.x);
    o[1] = (short)f2bf(v.y);
    o[2] = (short)f2bf(v.z);
    o[3] = (short)f2bf(v.w);
    *(short4v*)(out + i) = o;
}

// ---------- GEMM: Y[m][n] = sum_k A[m][k] * W[n][k]  (y = A @ W^T) ----------
// A: [M][512] bf16 row-major.  W: [512][512] bf16 row-major.
// 128x64 block tile; each wave computes 32x64 (2 row-frags reuse every B-frag).
// MODE 0: out = bf16, head-split [B][H][T][D]   (Q, K)
// MODE 2: out = bf16, head-split transposed [B][H][D][T]  (V^T)
// MODE 3: out = f32 row-major [M][512]          (final output)
template<int MODE>
__global__ __launch_bounds__(256) void gemm_bt(const unsigned short* __restrict__ A,
                                               const unsigned short* __restrict__ W,
                                               void* __restrict__ out) {
    const int wave = threadIdx.x >> 6;
    const int lane = threadIdx.x & 63;
    const int g    = lane >> 4;    // 0..3 (k-group)
    const int lr   = lane & 15;    // 0..15
    const int row0 = blockIdx.x * 128 + wave * 32;
    const int col0 = blockIdx.y * 64;

    f32x4 acc[2][4];
#pragma unroll
    for (int r = 0; r < 2; ++r)
#pragma unroll
        for (int i = 0; i < 4; ++i) acc[r][i] = (f32x4){0.f, 0.f, 0.f, 0.f};

    const unsigned short* Arow0 = A + (size_t)(row0 + lr) * C_DIM;
    const unsigned short* Arow1 = A + (size_t)(row0 + 16 + lr) * C_DIM;
#pragma unroll 4
    for (int kk = 0; kk < C_DIM; kk += 32) {
        bf16x8 a0 = *(const bf16x8*)(Arow0 + kk + g * 8);
        bf16x8 a1 = *(const bf16x8*)(Arow1 + kk + g * 8);
#pragma unroll
        for (int nt = 0; nt < 4; ++nt) {
            const unsigned short* Wrow = W + (size_t)(col0 + nt * 16 + lr) * C_DIM;
            bf16x8 b = *(const bf16x8*)(Wrow + kk + g * 8);
            acc[0][nt] = __builtin_amdgcn_mfma_f32_16x16x32_bf16(a0, b, acc[0][nt], 0, 0, 0);
            acc[1][nt] = __builtin_amdgcn_mfma_f32_16x16x32_bf16(a1, b, acc[1][nt], 0, 0, 0);
        }
    }

#pragma unroll
    for (int ar = 0; ar < 2; ++ar) {
        const int rowb = row0 + ar * 16;
#pragma unroll
        for (int nt = 0; nt < 4; ++nt) {
            const int n = col0 + nt * 16 + lr;
            if (MODE == 3) {
                float* O = (float*)out;
#pragma unroll
                for (int j = 0; j < 4; ++j) {
                    int m = rowb + g * 4 + j;
                    O[(size_t)m * C_DIM + n] = acc[ar][nt][j];
                }
            } else {
                const int h = n >> 6, d = n & 63;
                unsigned short* O = (unsigned short*)out;
                if (MODE == 0) {
#pragma unroll
                    for (int j = 0; j < 4; ++j) {
                        int m = rowb + g * 4 + j;
                        int b = m >> 12, t = m & (T_DIM - 1);
                        O[((size_t)(b * H_DIM + h) * T_DIM + t) * D_DIM + d] = f2bf(acc[ar][nt][j]);
                    }
                } else {  // MODE 2: V transposed [B][H][D][T]
                    int m = rowb + g * 4;
                    int b = m >> 12, t = m & (T_DIM - 1);
                    short4v pack;
#pragma unroll
                    for (int j = 0; j < 4; ++j) pack[j] = (short)f2bf(acc[ar][nt][j]);
                    *(short4v*)(O + ((size_t)(b * H_DIM + h) * D_DIM + d) * T_DIM + t) = pack;
                }
            }
        }
    }
}

// ---------- causal flash attention ----------
// Q,K: [B*H][T][D] bf16.  Vt: [B*H][D][T] bf16.  attn out: [B*T][C] bf16 (merged heads).
// One wave owns 16 q rows; block = 4 waves = 64 q rows of one head.
// Longest-first: q-block index descends with blockIdx so causal tails pack well.
// Swapped QK^T: S^T = mfma(K, Q); C-frag holds S[kv0+i*16+g*4+j][q0+lr].
// KVBLK=64 per iteration: 8 S-MFMAs + single merged softmax pass + 8 PV-MFMAs.
__global__ __launch_bounds__(256) void attn_kernel(const unsigned short* __restrict__ Qh,
                                                   const unsigned short* __restrict__ Kh,
                                                   const unsigned short* __restrict__ Vt,
                                                   unsigned short* __restrict__ attn) {
    const int wav  = threadIdx.x >> 6;
    const int lane = threadIdx.x & 63;
    const int g    = lane >> 4;
    const int lr   = lane & 15;
    const int nqb  = T_DIM / 64;                       // 64 q-blocks per head
    const int qb   = nqb - 1 - (int)(blockIdx.x >> 4); // descending: longest first
    const int bh   = blockIdx.x & 15;
    const int q0   = qb * 64 + wav * 16;
    const int q    = q0 + lr;

    const unsigned short* Qp = Qh + (size_t)bh * T_DIM * D_DIM;
    const unsigned short* Kp = Kh + (size_t)bh * T_DIM * D_DIM;
    const unsigned short* Vp = Vt + (size_t)bh * D_DIM * T_DIM;

    // Q as B-operand: col = q0+lr, k = d
    const bf16x8 qf0 = *(const bf16x8*)(Qp + (size_t)(q0 + lr) * D_DIM + g * 8);
    const bf16x8 qf1 = *(const bf16x8*)(Qp + (size_t)(q0 + lr) * D_DIM + 32 + g * 8);

    f32x4 o[4];
#pragma unroll
    for (int i = 0; i < 4; ++i) o[i] = (f32x4){0.f, 0.f, 0.f, 0.f};
    float mrun = -INFINITY, lrun = 0.f;

    const int kvend = q0 + 16;   // exclusive causal kv limit for this wave

    for (int kv0 = 0; kv0 < kvend; kv0 += 64) {
        // ---- QK^T for 64 kv rows (4 row-groups of 16) ----
        f32x4 s[4];
#pragma unroll
        for (int i = 0; i < 4; ++i) s[i] = (f32x4){0.f, 0.f, 0.f, 0.f};
#pragma unroll
        for (int i = 0; i < 4; ++i) {
            const unsigned short* Kr = Kp + (size_t)(kv0 + i * 16 + lr) * D_DIM;
            s[i] = __builtin_amdgcn_mfma_f32_16x16x32_bf16(*(const bf16x8*)(Kr + g * 8),      qf0, s[i], 0, 0, 0);
            s[i] = __builtin_amdgcn_mfma_f32_16x16x32_bf16(*(const bf16x8*)(Kr + 32 + g * 8), qf1, s[i], 0, 0, 0);
        }

        // ---- V prefetch for both 32-halves (independent of softmax) ----
        short4v vlo[2][4], vhi[2][4];
#pragma unroll
        for (int h = 0; h < 2; ++h)
#pragma unroll
            for (int d0 = 0; d0 < 4; ++d0) {
                const unsigned short* Vr = Vp + (size_t)(d0 * 16 + lr) * T_DIM + kv0 + h * 32 + g * 4;
                vlo[h][d0] = *(const short4v*)(Vr);
                vhi[h][d0] = *(const short4v*)(Vr + 16);
            }

        // ---- mask + scale (mask only on the diagonal block) ----
        float z[16];
        if (kv0 + 63 > q0) {
#pragma unroll
            for (int i = 0; i < 4; ++i)
#pragma unroll
                for (int j = 0; j < 4; ++j) {
                    int kva = kv0 + i * 16 + g * 4 + j;
                    z[i * 4 + j] = (kva > q) ? -INFINITY : s[i][j] * 0.125f;
                }
        } else {
#pragma unroll
            for (int i = 0; i < 4; ++i)
#pragma unroll
                for (int j = 0; j < 4; ++j)
                    z[i * 4 + j] = s[i][j] * 0.125f;
        }

        // ---- merged online softmax over 64 kv ----
        float mt = z[0];
#pragma unroll
        for (int j = 1; j < 16; ++j) mt = fmaxf(mt, z[j]);
        mt = fmaxf(mt, __shfl_xor(mt, 16));
        mt = fmaxf(mt, __shfl_xor(mt, 32));
        const float mnew  = fmaxf(mrun, mt);
        const float alpha = exp2f((mrun - mnew) * 1.44269504f);

        bf16x8 pf0, pf1;
        float psum = 0.f;
#pragma unroll
        for (int j = 0; j < 8; ++j) {
            float p = exp2f((z[j] - mnew) * 1.44269504f);
            psum += p;
            pf0[j] = (short)f2bf(p);
        }
#pragma unroll
        for (int j = 0; j < 8; ++j) {
            float p = exp2f((z[8 + j] - mnew) * 1.44269504f);
            psum += p;
            pf1[j] = (short)f2bf(p);
        }
        psum += __shfl_xor(psum, 16);
        psum += __shfl_xor(psum, 32);
        lrun = lrun * alpha + psum;
        mrun = mnew;
#pragma unroll
        for (int i = 0; i < 4; ++i) {
            o[i][0] *= alpha; o[i][1] *= alpha; o[i][2] *= alpha; o[i][3] *= alpha;
        }

        // ---- PV: O^T += V^T * P^T (consistent custom k mapping on A and B) ----
#pragma unroll
        for (int d0 = 0; d0 < 4; ++d0) {
            bf16x8 vf;
            vf[0] = vlo[0][d0][0]; vf[1] = vlo[0][d0][1]; vf[2] = vlo[0][d0][2]; vf[3] = vlo[0][d0][3];
            vf[4] = vhi[0][d0][0]; vf[5] = vhi[0][d0][1]; vf[6] = vhi[0][d0][2]; vf[7] = vhi[0][d0][3];
            o[d0] = __builtin_amdgcn_mfma_f32_16x16x32_bf16(vf, pf0, o[d0], 0, 0, 0);
        }
#pragma unroll
        for (int d0 = 0; d0 < 4; ++d0) {
            bf16x8 vf;
            vf[0] = vlo[1][d0][0]; vf[1] = vlo[1][d0][1]; vf[2] = vlo[1][d0][2]; vf[3] = vlo[1][d0][3];
            vf[4] = vhi[1][d0][0]; vf[5] = vhi[1][d0][1]; vf[6] = vhi[1][d0][2]; vf[7] = vhi[1][d0][3];
            o[d0] = __builtin_amdgcn_mfma_f32_16x16x32_bf16(vf, pf1, o[d0], 0, 0, 0);
        }
    }

    const float inv = 1.0f / lrun;
    const int b = bh >> 3, h = bh & 7;
    unsigned short* orow = attn + ((size_t)(b * T_DIM + q0 + lr)) * C_DIM + h * D_DIM;
#pragma unroll
    for (int d0 = 0; d0 < 4; ++d0)
#pragma unroll
        for (int j = 0; j < 4; ++j)
            orow[d0 * 16 + g * 4 + j] = f2bf(o[d0][j] * inv);
}

// ---------- launch ----------
extern "C" void kernel_launch(void* const* d_in, const int* in_sizes, int n_in,
                              void* d_out, int out_size, void* d_ws, size_t ws_size,
                              hipStream_t stream) {
    const float* x  = (const float*)d_in[0];
    const float* Wq = (const float*)d_in[1];
    const float* Wk = (const float*)d_in[2];
    const float* Wv = (const float*)d_in[3];
    const float* Wo = (const float*)d_in[4];

    char* ws = (char*)d_ws;
    // workspace layout (bytes)
    unsigned short* xb    = (unsigned short*)(ws + 0);         //  8 MB  x bf16 [8192][512]
    unsigned short* Wqb   = (unsigned short*)(ws + 8388608);   // 512 KB
    unsigned short* Wkb   = (unsigned short*)(ws + 8912896);
    unsigned short* Wvb   = (unsigned short*)(ws + 9437184);
    unsigned short* Wob   = (unsigned short*)(ws + 9961472);
    unsigned short* Qh    = (unsigned short*)(ws + 10485760);  //  8 MB [B][H][T][D]
    unsigned short* Kh    = (unsigned short*)(ws + 18874368);  //  8 MB
    unsigned short* Vt    = (unsigned short*)(ws + 27262976);  //  8 MB [B][H][D][T]
    unsigned short* attnb = (unsigned short*)(ws + 35651584);  //  8 MB [8192][512]

    const int nX = M_DIM * C_DIM;      // 4194304
    const int nW = C_DIM * C_DIM;      // 262144

    cvt_kernel<<<nX / 4 / 256, 256, 0, stream>>>(x, xb, nX);
    cvt_kernel<<<nW / 4 / 256, 256, 0, stream>>>(Wq, Wqb, nW);
    cvt_kernel<<<nW / 4 / 256, 256, 0, stream>>>(Wk, Wkb, nW);
    cvt_kernel<<<nW / 4 / 256, 256, 0, stream>>>(Wv, Wvb, nW);
    cvt_kernel<<<nW / 4 / 256, 256, 0, stream>>>(Wo, Wob, nW);

    dim3 ggrid(M_DIM / 128, C_DIM / 64);
    gemm_bt<0><<<ggrid, 256, 0, stream>>>(xb, Wqb, Qh);
    gemm_bt<0><<<ggrid, 256, 0, stream>>>(xb, Wkb, Kh);
    gemm_bt<2><<<ggrid, 256, 0, stream>>>(xb, Wvb, Vt);

    attn_kernel<<<B_DIM * H_DIM * (T_DIM / 64), 256, 0, stream>>>(Qh, Kh, Vt, attnb);

    gemm_bt<3><<<ggrid, 256, 0, stream>>>(attnb, Wob, d_out);
}

// Round 4
// 266.476 us; speedup vs baseline: 3.1234x; 1.8980x over previous
//
#include <hip/hip_runtime.h>
#include <stdint.h>

// ---------- problem constants ----------
#define B_DIM 2
#define T_DIM 4096
#define C_DIM 512
#define H_DIM 8
#define D_DIM 64
#define M_DIM (B_DIM * T_DIM)   // 8192

typedef __attribute__((ext_vector_type(8))) short bf16x8;   // MFMA A/B frag (8 bf16)
typedef __attribute__((ext_vector_type(4))) float f32x4;    // MFMA C/D frag
typedef __attribute__((ext_vector_type(4))) short short4v;  // 8B vector

__device__ inline unsigned short f2bf(float f) {
    union { float f; uint32_t u; } v; v.f = f;
    uint32_t r = v.u + 0x7fffu + ((v.u >> 16) & 1u);   // RNE
    return (unsigned short)(r >> 16);
}

__device__ inline uint32_t packbf(float a, float b) {
    return (uint32_t)f2bf(a) | ((uint32_t)f2bf(b) << 16);
}

// ---------- f32 -> bf16 conversion ----------
__global__ __launch_bounds__(256) void cvt_kernel(const float* __restrict__ in,
                                                  unsigned short* __restrict__ out, int n) {
    int i = (blockIdx.x * 256 + threadIdx.x) * 4;
    if (i >= n) return;
    float4 v = *(const float4*)(in + i);
    short4v o;
    o[0] = (short)f2bf(v.x);
    o[1] = (short)f2bf(v.y);
    o[2] = (short)f2bf(v.z);
    o[3] = (short)f2bf(v.w);
    *(short4v*)(out + i) = o;
}

// ---------- GEMM: Y[m][n] = sum_k A[m][k] * W[n][k]  (y = A @ W^T) ----------
// A: [M][512] bf16 row-major.  W: [512][512] bf16 row-major.
// 128x64 block tile; each wave computes 32x64 (2 row-frags reuse every B-frag).
// MODE 0: out = bf16, head-split [B][H][T][D]   (Q, K)
// MODE 2: out = bf16, head-split transposed + kv-permuted [B][H][D][T']  (V^T)
//         within each 32-col group, column kv is stored at position
//         p = ((kv>>2)&3)*8 + ((kv>>4)&1)*4 + (kv&3)  so the attn PV A-frag
//         is one contiguous 16B lane load (matches B-frag k mapping).
// MODE 3: out = f32 row-major [M][512]          (final output)
template<int MODE>
__global__ __launch_bounds__(256) void gemm_bt(const unsigned short* __restrict__ A,
                                               const unsigned short* __restrict__ W,
                                               void* __restrict__ out) {
    const int wave = threadIdx.x >> 6;
    const int lane = threadIdx.x & 63;
    const int g    = lane >> 4;    // 0..3 (k-group)
    const int lr   = lane & 15;    // 0..15
    const int row0 = blockIdx.x * 128 + wave * 32;
    const int col0 = blockIdx.y * 64;

    f32x4 acc[2][4];
#pragma unroll
    for (int r = 0; r < 2; ++r)
#pragma unroll
        for (int i = 0; i < 4; ++i) acc[r][i] = (f32x4){0.f, 0.f, 0.f, 0.f};

    const unsigned short* Arow0 = A + (size_t)(row0 + lr) * C_DIM;
    const unsigned short* Arow1 = A + (size_t)(row0 + 16 + lr) * C_DIM;
#pragma unroll 4
    for (int kk = 0; kk < C_DIM; kk += 32) {
        bf16x8 a0 = *(const bf16x8*)(Arow0 + kk + g * 8);
        bf16x8 a1 = *(const bf16x8*)(Arow1 + kk + g * 8);
#pragma unroll
        for (int nt = 0; nt < 4; ++nt) {
            const unsigned short* Wrow = W + (size_t)(col0 + nt * 16 + lr) * C_DIM;
            bf16x8 b = *(const bf16x8*)(Wrow + kk + g * 8);
            acc[0][nt] = __builtin_amdgcn_mfma_f32_16x16x32_bf16(a0, b, acc[0][nt], 0, 0, 0);
            acc[1][nt] = __builtin_amdgcn_mfma_f32_16x16x32_bf16(a1, b, acc[1][nt], 0, 0, 0);
        }
    }

#pragma unroll
    for (int ar = 0; ar < 2; ++ar) {
        const int rowb = row0 + ar * 16;
#pragma unroll
        for (int nt = 0; nt < 4; ++nt) {
            const int n = col0 + nt * 16 + lr;
            if (MODE == 3) {
                float* O = (float*)out;
#pragma unroll
                for (int j = 0; j < 4; ++j) {
                    int m = rowb + g * 4 + j;
                    O[(size_t)m * C_DIM + n] = acc[ar][nt][j];
                }
            } else {
                const int h = n >> 6, d = n & 63;
                unsigned short* O = (unsigned short*)out;
                if (MODE == 0) {
#pragma unroll
                    for (int j = 0; j < 4; ++j) {
                        int m = rowb + g * 4 + j;
                        int b = m >> 12, t = m & (T_DIM - 1);
                        O[((size_t)(b * H_DIM + h) * T_DIM + t) * D_DIM + d] = f2bf(acc[ar][nt][j]);
                    }
                } else {  // MODE 2: V transposed + permuted [B][H][D][T']
                    int m = rowb + g * 4;
                    int b = m >> 12, t = m & (T_DIM - 1);
                    int tp = (t & ~31) | (((t >> 2) & 3) << 3) | (((t >> 4) & 1) << 2);
                    short4v pack;
#pragma unroll
                    for (int j = 0; j < 4; ++j) pack[j] = (short)f2bf(acc[ar][nt][j]);
                    *(short4v*)(O + ((size_t)(b * H_DIM + h) * D_DIM + d) * T_DIM + tp) = pack;
                }
            }
        }
    }
}

// ---------- causal flash attention ----------
// Q,K: [B*H][T][D] bf16.  Vt: [B*H][D][T'] bf16 (kv-permuted).  attn out: [B*T][C] bf16.
// One 64-lane wave per block owns 32 q rows (2 q-frag chains sharing all K/V frags).
// Swapped QK^T: S^T = mfma(K, Q); C-frag holds S[kv0+i*16+g*4+j][q0+lr].
// Raw-score domain; scale*log2(e) folded into the exp (KC). Always-rescale online
// softmax with -INF masks (NaN-safe: exp2f(-inf)=0). VALU psum + 2 shuffles.
__global__ __launch_bounds__(64, 2) void attn_kernel(const unsigned short* __restrict__ Qh,
                                                     const unsigned short* __restrict__ Kh,
                                                     const unsigned short* __restrict__ Vt,
                                                     unsigned short* __restrict__ attn) {
    const int lane = threadIdx.x;   // 0..63
    const int g    = lane >> 4;
    const int lr   = lane & 15;
    const int bh   = blockIdx.x & 15;
    const int ord  = blockIdx.x >> 4;                              // 0..127
    const int qb   = (ord < 64) ? (127 - 2 * ord) : (2 * (ord - 64));  // balanced longest-first
    const int qw   = qb * 32;

    const unsigned short* Qp = Qh + (size_t)bh * T_DIM * D_DIM;
    const unsigned short* Kp = Kh + (size_t)bh * T_DIM * D_DIM;
    const unsigned short* Vp = Vt + (size_t)bh * D_DIM * T_DIM;

    bf16x8 qf[2][2];
#pragma unroll
    for (int h = 0; h < 2; ++h)
#pragma unroll
        for (int dh = 0; dh < 2; ++dh)
            qf[h][dh] = *(const bf16x8*)(Qp + (size_t)(qw + h * 16 + lr) * D_DIM + dh * 32 + g * 8);

    f32x4 o[2][4];
#pragma unroll
    for (int h = 0; h < 2; ++h)
#pragma unroll
        for (int i = 0; i < 4; ++i) o[h][i] = (f32x4){0.f, 0.f, 0.f, 0.f};
    float mrun[2] = {-INFINITY, -INFINITY};
    float lrun[2] = {0.f, 0.f};

    const float KC = 0.125f * 1.44269504f;   // scale * log2(e)
    const int kvend = qw + 32;

    // prologue: K frags for kv0 = 0
    bf16x8 kc8[4][2];
#pragma unroll
    for (int i = 0; i < 4; ++i)
#pragma unroll
        for (int dh = 0; dh < 2; ++dh)
            kc8[i][dh] = *(const bf16x8*)(Kp + (size_t)(i * 16 + lr) * D_DIM + dh * 32 + g * 8);

    for (int kv0 = 0; kv0 < kvend; kv0 += 64) {
        // ---- issue next-iteration K loads (wrap to 0 on last iter; harmless) ----
        const int kvn = (kv0 + 64 < kvend) ? kv0 + 64 : 0;
        bf16x8 kn8[4][2];
#pragma unroll
        for (int i = 0; i < 4; ++i)
#pragma unroll
            for (int dh = 0; dh < 2; ++dh)
                kn8[i][dh] = *(const bf16x8*)(Kp + (size_t)(kvn + i * 16 + lr) * D_DIM + dh * 32 + g * 8);

        // ---- QK^T: both q-halves share every K frag ----
        f32x4 s[2][4];
#pragma unroll
        for (int h = 0; h < 2; ++h)
#pragma unroll
            for (int i = 0; i < 4; ++i) s[h][i] = (f32x4){0.f, 0.f, 0.f, 0.f};
#pragma unroll
        for (int i = 0; i < 4; ++i) {
            s[0][i] = __builtin_amdgcn_mfma_f32_16x16x32_bf16(kc8[i][0], qf[0][0], s[0][i], 0, 0, 0);
            s[0][i] = __builtin_amdgcn_mfma_f32_16x16x32_bf16(kc8[i][1], qf[0][1], s[0][i], 0, 0, 0);
            s[1][i] = __builtin_amdgcn_mfma_f32_16x16x32_bf16(kc8[i][0], qf[1][0], s[1][i], 0, 0, 0);
            s[1][i] = __builtin_amdgcn_mfma_f32_16x16x32_bf16(kc8[i][1], qf[1][1], s[1][i], 0, 0, 0);
        }

        // ---- issue V loads (permuted layout: one 16B load per PV A-frag) ----
        bf16x8 vf[2][4];
#pragma unroll
        for (int kh = 0; kh < 2; ++kh)
#pragma unroll
            for (int d0 = 0; d0 < 4; ++d0)
                vf[kh][d0] = *(const bf16x8*)(Vp + (size_t)(d0 * 16 + lr) * T_DIM + kv0 + kh * 32 + g * 8);

        const bool maskit = (kv0 + 63 > qw);

#pragma unroll
        for (int h = 0; h < 2; ++h) {
            const int qh = qw + h * 16 + lr;
            float z[16];
            if (maskit) {
#pragma unroll
                for (int i = 0; i < 4; ++i)
#pragma unroll
                    for (int j = 0; j < 4; ++j) {
                        int kva = kv0 + i * 16 + g * 4 + j;
                        z[i * 4 + j] = (kva > qh) ? -INFINITY : s[h][i][j];
                    }
            } else {
#pragma unroll
                for (int i = 0; i < 4; ++i)
#pragma unroll
                    for (int j = 0; j < 4; ++j) z[i * 4 + j] = s[h][i][j];
            }

            // row max (raw domain), cross-lane over the 4 g-groups
            float a0 = fmaxf(fmaxf(z[0], z[1]), z[2]);
            float a1 = fmaxf(fmaxf(z[3], z[4]), z[5]);
            float a2 = fmaxf(fmaxf(z[6], z[7]), z[8]);
            float a3 = fmaxf(fmaxf(z[9], z[10]), z[11]);
            float a4 = fmaxf(fmaxf(z[12], z[13]), z[14]);
            float b0 = fmaxf(fmaxf(a0, a1), z[15]);
            float b1 = fmaxf(fmaxf(a2, a3), a4);
            float mt = fmaxf(b0, b1);
            mt = fmaxf(mt, __shfl_xor(mt, 16));
            mt = fmaxf(mt, __shfl_xor(mt, 32));

            const float mnew  = fmaxf(mrun[h], mt);           // finite after block 0
            const float alpha = exp2f((mrun[h] - mnew) * KC); // block 0: exp2f(-inf)=0
            mrun[h] = mnew;

            const float mb = -mnew * KC;
            float p[16];
#pragma unroll
            for (int e = 0; e < 16; ++e) p[e] = exp2f(fmaf(z[e], KC, mb)); // masked -> 0

            float psum = ((p[0] + p[1]) + (p[2] + p[3])) + ((p[4] + p[5]) + (p[6] + p[7]))
                       + ((p[8] + p[9]) + (p[10] + p[11])) + ((p[12] + p[13]) + (p[14] + p[15]));
            psum += __shfl_xor(psum, 16);
            psum += __shfl_xor(psum, 32);
            lrun[h] = lrun[h] * alpha + psum;

#pragma unroll
            for (int d0 = 0; d0 < 4; ++d0)
#pragma unroll
                for (int j = 0; j < 4; ++j) o[h][d0][j] *= alpha;

            union { bf16x8 v; uint32_t w[4]; } pf0, pf1;
#pragma unroll
            for (int w = 0; w < 4; ++w) pf0.w[w] = packbf(p[2 * w], p[2 * w + 1]);
#pragma unroll
            for (int w = 0; w < 4; ++w) pf1.w[w] = packbf(p[8 + 2 * w], p[9 + 2 * w]);

            // PV: O^T += V^T * P^T (identical custom k mapping on A and B)
#pragma unroll
            for (int d0 = 0; d0 < 4; ++d0)
                o[h][d0] = __builtin_amdgcn_mfma_f32_16x16x32_bf16(vf[0][d0], pf0.v, o[h][d0], 0, 0, 0);
#pragma unroll
            for (int d0 = 0; d0 < 4; ++d0)
                o[h][d0] = __builtin_amdgcn_mfma_f32_16x16x32_bf16(vf[1][d0], pf1.v, o[h][d0], 0, 0, 0);
        }

        // rotate prefetched K into current
#pragma unroll
        for (int i = 0; i < 4; ++i)
#pragma unroll
            for (int dh = 0; dh < 2; ++dh) kc8[i][dh] = kn8[i][dh];
    }

    // ---- epilogue: normalize, pack, store ----
    const int b = bh >> 3, hh = bh & 7;
#pragma unroll
    for (int h = 0; h < 2; ++h) {
        const float inv = 1.0f / lrun[h];
        unsigned short* orow = attn + ((size_t)(b * T_DIM + qw + h * 16 + lr)) * C_DIM + hh * D_DIM;
#pragma unroll
        for (int d0 = 0; d0 < 4; ++d0) {
            uint2 st;
            st.x = packbf(o[h][d0][0] * inv, o[h][d0][1] * inv);
            st.y = packbf(o[h][d0][2] * inv, o[h][d0][3] * inv);
            *(uint2*)(orow + d0 * 16 + g * 4) = st;
        }
    }
}

// ---------- launch ----------
extern "C" void kernel_launch(void* const* d_in, const int* in_sizes, int n_in,
                              void* d_out, int out_size, void* d_ws, size_t ws_size,
                              hipStream_t stream) {
    const float* x  = (const float*)d_in[0];
    const float* Wq = (const float*)d_in[1];
    const float* Wk = (const float*)d_in[2];
    const float* Wv = (const float*)d_in[3];
    const float* Wo = (const float*)d_in[4];

    char* ws = (char*)d_ws;
    // workspace layout (bytes)
    unsigned short* xb    = (unsigned short*)(ws + 0);         //  8 MB  x bf16 [8192][512]
    unsigned short* Wqb   = (unsigned short*)(ws + 8388608);   // 512 KB
    unsigned short* Wkb   = (unsigned short*)(ws + 8912896);
    unsigned short* Wvb   = (unsigned short*)(ws + 9437184);
    unsigned short* Wob   = (unsigned short*)(ws + 9961472);
    unsigned short* Qh    = (unsigned short*)(ws + 10485760);  //  8 MB [B][H][T][D]
    unsigned short* Kh    = (unsigned short*)(ws + 18874368);  //  8 MB
    unsigned short* Vt    = (unsigned short*)(ws + 27262976);  //  8 MB [B][H][D][T'] permuted
    unsigned short* attnb = (unsigned short*)(ws + 35651584);  //  8 MB [8192][512]

    const int nX = M_DIM * C_DIM;      // 4194304
    const int nW = C_DIM * C_DIM;      // 262144

    cvt_kernel<<<nX / 4 / 256, 256, 0, stream>>>(x, xb, nX);
    cvt_kernel<<<nW / 4 / 256, 256, 0, stream>>>(Wq, Wqb, nW);
    cvt_kernel<<<nW / 4 / 256, 256, 0, stream>>>(Wk, Wkb, nW);
    cvt_kernel<<<nW / 4 / 256, 256, 0, stream>>>(Wv, Wvb, nW);
    cvt_kernel<<<nW / 4 / 256, 256, 0, stream>>>(Wo, Wob, nW);

    dim3 ggrid(M_DIM / 128, C_DIM / 64);
    gemm_bt<0><<<ggrid, 256, 0, stream>>>(xb, Wqb, Qh);
    gemm_bt<0><<<ggrid, 256, 0, stream>>>(xb, Wkb, Kh);
    gemm_bt<2><<<ggrid, 256, 0, stream>>>(xb, Wvb, Vt);

    attn_kernel<<<B_DIM * H_DIM * (T_DIM / 32), 64, 0, stream>>>(Qh, Kh, Vt, attnb);

    gemm_bt<3><<<ggrid, 256, 0, stream>>>(attnb, Wob, d_out);
}

// Round 5
// 248.844 us; speedup vs baseline: 3.3447x; 1.0709x over previous
//
#include <hip/hip_runtime.h>
#include <stdint.h>

// ---------- problem constants ----------
#define B_DIM 2
#define T_DIM 4096
#define C_DIM 512
#define H_DIM 8
#define D_DIM 64
#define M_DIM (B_DIM * T_DIM)   // 8192

typedef __attribute__((ext_vector_type(8))) short bf16x8;   // MFMA A/B frag (8 bf16)
typedef __attribute__((ext_vector_type(4))) float f32x4;    // MFMA C/D frag
typedef __attribute__((ext_vector_type(4))) short short4v;  // 8B vector

__device__ inline unsigned short f2bf(float f) {
    union { float f; uint32_t u; } v; v.f = f;
    uint32_t r = v.u + 0x7fffu + ((v.u >> 16) & 1u);   // RNE
    return (unsigned short)(r >> 16);
}

__device__ inline uint32_t packbf(float a, float b) {
    return (uint32_t)f2bf(a) | ((uint32_t)f2bf(b) << 16);
}

// ---------- f32 -> bf16 conversion ----------
__global__ __launch_bounds__(256) void cvt_kernel(const float* __restrict__ in,
                                                  unsigned short* __restrict__ out, int n) {
    int i = (blockIdx.x * 256 + threadIdx.x) * 4;
    if (i >= n) return;
    float4 v = *(const float4*)(in + i);
    short4v o;
    o[0] = (short)f2bf(v.x);
    o[1] = (short)f2bf(v.y);
    o[2] = (short)f2bf(v.z);
    o[3] = (short)f2bf(v.w);
    *(short4v*)(out + i) = o;
}

// ---------- GEMM: Y[m][n] = sum_k A[m][k] * W[n][k]  (y = A @ W^T) ----------
// A: [M][512] bf16 row-major.  W: [512][512] bf16 row-major.
// 128x64 block tile; each wave computes 32x64 (2 row-frags reuse every B-frag).
// MODE 0: out = bf16, head-split [B][H][T][D]   (Q, K)
// MODE 2: out = bf16, head-split transposed + kv-permuted [B][H][D][T']  (V^T)
//         within each 32-col group, column kv is stored at position
//         p = ((kv>>2)&3)*8 + ((kv>>4)&1)*4 + (kv&3)  so the attn PV A-frag
//         is one contiguous 16B lane load (matches B-frag k mapping).
// MODE 3: out = f32 row-major [M][512]          (final output)
template<int MODE>
__global__ __launch_bounds__(256) void gemm_bt(const unsigned short* __restrict__ A,
                                               const unsigned short* __restrict__ W,
                                               void* __restrict__ out) {
    const int wave = threadIdx.x >> 6;
    const int lane = threadIdx.x & 63;
    const int g    = lane >> 4;    // 0..3 (k-group)
    const int lr   = lane & 15;    // 0..15
    const int row0 = blockIdx.x * 128 + wave * 32;
    const int col0 = blockIdx.y * 64;

    f32x4 acc[2][4];
#pragma unroll
    for (int r = 0; r < 2; ++r)
#pragma unroll
        for (int i = 0; i < 4; ++i) acc[r][i] = (f32x4){0.f, 0.f, 0.f, 0.f};

    const unsigned short* Arow0 = A + (size_t)(row0 + lr) * C_DIM;
    const unsigned short* Arow1 = A + (size_t)(row0 + 16 + lr) * C_DIM;
#pragma unroll 4
    for (int kk = 0; kk < C_DIM; kk += 32) {
        bf16x8 a0 = *(const bf16x8*)(Arow0 + kk + g * 8);
        bf16x8 a1 = *(const bf16x8*)(Arow1 + kk + g * 8);
#pragma unroll
        for (int nt = 0; nt < 4; ++nt) {
            const unsigned short* Wrow = W + (size_t)(col0 + nt * 16 + lr) * C_DIM;
            bf16x8 b = *(const bf16x8*)(Wrow + kk + g * 8);
            acc[0][nt] = __builtin_amdgcn_mfma_f32_16x16x32_bf16(a0, b, acc[0][nt], 0, 0, 0);
            acc[1][nt] = __builtin_amdgcn_mfma_f32_16x16x32_bf16(a1, b, acc[1][nt], 0, 0, 0);
        }
    }

#pragma unroll
    for (int ar = 0; ar < 2; ++ar) {
        const int rowb = row0 + ar * 16;
#pragma unroll
        for (int nt = 0; nt < 4; ++nt) {
            const int n = col0 + nt * 16 + lr;
            if (MODE == 3) {
                float* O = (float*)out;
#pragma unroll
                for (int j = 0; j < 4; ++j) {
                    int m = rowb + g * 4 + j;
                    O[(size_t)m * C_DIM + n] = acc[ar][nt][j];
                }
            } else {
                const int h = n >> 6, d = n & 63;
                unsigned short* O = (unsigned short*)out;
                if (MODE == 0) {
#pragma unroll
                    for (int j = 0; j < 4; ++j) {
                        int m = rowb + g * 4 + j;
                        int b = m >> 12, t = m & (T_DIM - 1);
                        O[((size_t)(b * H_DIM + h) * T_DIM + t) * D_DIM + d] = f2bf(acc[ar][nt][j]);
                    }
                } else {  // MODE 2: V transposed + permuted [B][H][D][T']
                    int m = rowb + g * 4;
                    int b = m >> 12, t = m & (T_DIM - 1);
                    int tp = (t & ~31) | (((t >> 2) & 3) << 3) | (((t >> 4) & 1) << 2);
                    short4v pack;
#pragma unroll
                    for (int j = 0; j < 4; ++j) pack[j] = (short)f2bf(acc[ar][nt][j]);
                    *(short4v*)(O + ((size_t)(b * H_DIM + h) * D_DIM + d) * T_DIM + tp) = pack;
                }
            }
        }
    }
}

// ---------- causal flash attention, parity-split uniform waves ----------
// Q,K: [B*H][T][D] bf16.  Vt: [B*H][D][T'] bf16 (kv-permuted).  attn out: [B*T][C] bf16.
// Block = 128 threads = 2 waves; block owns tile pair (qb=ord, 127-ord) of one head.
// Wave 0 processes kv-blocks of even parity (kv0 = 0,128,...), wave 1 odd (64,192,...)
// across BOTH tiles -> every wave ~32.5 iterations regardless of ord: uniform work,
// 2048 identical waves = 2/SIMD sustained, no tail. Partials merged in LDS.
// All softmax arithmetic kept finite (sentinel/mask = -1e30, never -inf) so empty or
// fully-masked parity ranges produce (o=0, m=-1e30, l=0) and merge weight exactly 0.
__global__ __launch_bounds__(128, 2) void attn_kernel(const unsigned short* __restrict__ Qh,
                                                      const unsigned short* __restrict__ Kh,
                                                      const unsigned short* __restrict__ Vt,
                                                      unsigned short* __restrict__ attn) {
    const int wave = threadIdx.x >> 6;   // parity: 0=even kv blocks, 1=odd
    const int lane = threadIdx.x & 63;
    const int g    = lane >> 4;
    const int lr   = lane & 15;
    const int bh   = blockIdx.x & 15;
    const int ord  = blockIdx.x >> 4;    // 0..63

    const unsigned short* Qp = Qh + (size_t)bh * T_DIM * D_DIM;
    const unsigned short* Kp = Kh + (size_t)bh * T_DIM * D_DIM;
    const unsigned short* Vp = Vt + (size_t)bh * D_DIM * T_DIM;

    const float KC = 0.125f * 1.44269504f;   // scale * log2(e)

    __shared__ float lds_o[2][2][64][17];    // [tile][h][lane][16 elems + pad]
    __shared__ float lds_m[2][2][16];
    __shared__ float lds_l[2][2][16];

    f32x4 oacc[2][2][4];
    float mR[2][2], lR[2][2];

#pragma unroll
    for (int t = 0; t < 2; ++t) {
        const int qb = (t == 0) ? ord : (127 - ord);
        const int qw = qb * 32;
        const int kvend = qw + 32;

        bf16x8 qf[2][2];
#pragma unroll
        for (int h = 0; h < 2; ++h)
#pragma unroll
            for (int dh = 0; dh < 2; ++dh)
                qf[h][dh] = *(const bf16x8*)(Qp + (size_t)(qw + h * 16 + lr) * D_DIM + dh * 32 + g * 8);

#pragma unroll
        for (int h = 0; h < 2; ++h) {
            oacc[t][h][0] = (f32x4){0.f, 0.f, 0.f, 0.f};
            oacc[t][h][1] = (f32x4){0.f, 0.f, 0.f, 0.f};
            oacc[t][h][2] = (f32x4){0.f, 0.f, 0.f, 0.f};
            oacc[t][h][3] = (f32x4){0.f, 0.f, 0.f, 0.f};
            mR[t][h] = -1e30f;
            lR[t][h] = 0.f;
        }

        const int kvstart = wave * 64;
        // prologue K frags (rows kvstart..kvstart+63 always < T_DIM)
        bf16x8 kc8[4][2];
#pragma unroll
        for (int i = 0; i < 4; ++i)
#pragma unroll
            for (int dh = 0; dh < 2; ++dh)
                kc8[i][dh] = *(const bf16x8*)(Kp + (size_t)(kvstart + i * 16 + lr) * D_DIM + dh * 32 + g * 8);

        for (int kv0 = kvstart; kv0 < kvend; kv0 += 128) {
            // ---- prefetch next-parity-iteration K (wrap harmlessly) ----
            const int kvn = (kv0 + 128 < kvend) ? kv0 + 128 : kvstart;
            bf16x8 kn8[4][2];
#pragma unroll
            for (int i = 0; i < 4; ++i)
#pragma unroll
                for (int dh = 0; dh < 2; ++dh)
                    kn8[i][dh] = *(const bf16x8*)(Kp + (size_t)(kvn + i * 16 + lr) * D_DIM + dh * 32 + g * 8);

            // ---- V loads (permuted layout: one 16B load per PV A-frag) ----
            bf16x8 vf[2][4];
#pragma unroll
            for (int kh = 0; kh < 2; ++kh)
#pragma unroll
                for (int d0 = 0; d0 < 4; ++d0)
                    vf[kh][d0] = *(const bf16x8*)(Vp + (size_t)(d0 * 16 + lr) * T_DIM + kv0 + kh * 32 + g * 8);

            // ---- QK^T: both q-halves share every K frag ----
            f32x4 s[2][4];
#pragma unroll
            for (int h = 0; h < 2; ++h)
#pragma unroll
                for (int i = 0; i < 4; ++i) s[h][i] = (f32x4){0.f, 0.f, 0.f, 0.f};
#pragma unroll
            for (int i = 0; i < 4; ++i) {
                s[0][i] = __builtin_amdgcn_mfma_f32_16x16x32_bf16(kc8[i][0], qf[0][0], s[0][i], 0, 0, 0);
                s[0][i] = __builtin_amdgcn_mfma_f32_16x16x32_bf16(kc8[i][1], qf[0][1], s[0][i], 0, 0, 0);
                s[1][i] = __builtin_amdgcn_mfma_f32_16x16x32_bf16(kc8[i][0], qf[1][0], s[1][i], 0, 0, 0);
                s[1][i] = __builtin_amdgcn_mfma_f32_16x16x32_bf16(kc8[i][1], qf[1][1], s[1][i], 0, 0, 0);
            }

            const bool maskit = (kv0 + 63 > qw);

#pragma unroll
            for (int h = 0; h < 2; ++h) {
                const int qh = qw + h * 16 + lr;
                float z[16];
                if (maskit) {
#pragma unroll
                    for (int i = 0; i < 4; ++i)
#pragma unroll
                        for (int j = 0; j < 4; ++j) {
                            int kva = kv0 + i * 16 + g * 4 + j;
                            z[i * 4 + j] = (kva > qh) ? -1e30f : s[h][i][j];
                        }
                } else {
#pragma unroll
                    for (int i = 0; i < 4; ++i)
#pragma unroll
                        for (int j = 0; j < 4; ++j) z[i * 4 + j] = s[h][i][j];
                }

                // row max (raw domain), cross-lane over the 4 g-groups
                float a0 = fmaxf(fmaxf(z[0], z[1]), z[2]);
                float a1 = fmaxf(fmaxf(z[3], z[4]), z[5]);
                float a2 = fmaxf(fmaxf(z[6], z[7]), z[8]);
                float a3 = fmaxf(fmaxf(z[9], z[10]), z[11]);
                float a4 = fmaxf(fmaxf(z[12], z[13]), z[14]);
                float b0 = fmaxf(fmaxf(a0, a1), z[15]);
                float b1 = fmaxf(fmaxf(a2, a3), a4);
                float mt = fmaxf(b0, b1);
                mt = fmaxf(mt, __shfl_xor(mt, 16));
                mt = fmaxf(mt, __shfl_xor(mt, 32));

                const float mnew  = fmaxf(mR[t][h], mt);            // finite always
                const float alpha = exp2f((mnew - mR[t][h]) * -KC); // 1.0 on first/empty
                mR[t][h] = mnew;

                const float mb = -mnew * KC;
                float p[16];
#pragma unroll
                for (int e = 0; e < 16; ++e) p[e] = exp2f(fmaf(z[e], KC, mb)); // masked -> 0

                float psum = ((p[0] + p[1]) + (p[2] + p[3])) + ((p[4] + p[5]) + (p[6] + p[7]))
                           + ((p[8] + p[9]) + (p[10] + p[11])) + ((p[12] + p[13]) + (p[14] + p[15]));
                psum += __shfl_xor(psum, 16);
                psum += __shfl_xor(psum, 32);
                lR[t][h] = lR[t][h] * alpha + psum;

#pragma unroll
                for (int d0 = 0; d0 < 4; ++d0)
#pragma unroll
                    for (int j = 0; j < 4; ++j) oacc[t][h][d0][j] *= alpha;

                union { bf16x8 v; uint32_t w[4]; } pf0, pf1;
#pragma unroll
                for (int w = 0; w < 4; ++w) pf0.w[w] = packbf(p[2 * w], p[2 * w + 1]);
#pragma unroll
                for (int w = 0; w < 4; ++w) pf1.w[w] = packbf(p[8 + 2 * w], p[9 + 2 * w]);

#pragma unroll
                for (int d0 = 0; d0 < 4; ++d0)
                    oacc[t][h][d0] = __builtin_amdgcn_mfma_f32_16x16x32_bf16(vf[0][d0], pf0.v, oacc[t][h][d0], 0, 0, 0);
#pragma unroll
                for (int d0 = 0; d0 < 4; ++d0)
                    oacc[t][h][d0] = __builtin_amdgcn_mfma_f32_16x16x32_bf16(vf[1][d0], pf1.v, oacc[t][h][d0], 0, 0, 0);
            }

#pragma unroll
            for (int i = 0; i < 4; ++i)
#pragma unroll
                for (int dh = 0; dh < 2; ++dh) kc8[i][dh] = kn8[i][dh];
        }
    }

    // ---- odd wave publishes partials ----
    if (wave == 1) {
#pragma unroll
        for (int t = 0; t < 2; ++t)
#pragma unroll
            for (int h = 0; h < 2; ++h) {
#pragma unroll
                for (int d0 = 0; d0 < 4; ++d0)
#pragma unroll
                    for (int j = 0; j < 4; ++j)
                        lds_o[t][h][lane][d0 * 4 + j] = oacc[t][h][d0][j];
                if (g == 0) {
                    lds_m[t][h][lr] = mR[t][h];
                    lds_l[t][h][lr] = lR[t][h];
                }
            }
    }
    __syncthreads();

    // ---- even wave merges and stores ----
    if (wave == 0) {
        const int b = bh >> 3, hh = bh & 7;
#pragma unroll
        for (int t = 0; t < 2; ++t) {
            const int qb = (t == 0) ? ord : (127 - ord);
            const int qw = qb * 32;
#pragma unroll
            for (int h = 0; h < 2; ++h) {
                const float m0 = mR[t][h], l0 = lR[t][h];
                const float m1 = lds_m[t][h][lr], l1 = lds_l[t][h][lr];
                const float mm = fmaxf(m0, m1);
                const float a0 = exp2f((m0 - mm) * KC);
                const float a1 = exp2f((m1 - mm) * KC);
                const float linv = 1.0f / (l0 * a0 + l1 * a1);
                unsigned short* orow = attn + ((size_t)(b * T_DIM + qw + h * 16 + lr)) * C_DIM + hh * D_DIM;
#pragma unroll
                for (int d0 = 0; d0 < 4; ++d0) {
                    float e0 = (oacc[t][h][d0][0] * a0 + lds_o[t][h][lane][d0 * 4 + 0] * a1) * linv;
                    float e1 = (oacc[t][h][d0][1] * a0 + lds_o[t][h][lane][d0 * 4 + 1] * a1) * linv;
                    float e2 = (oacc[t][h][d0][2] * a0 + lds_o[t][h][lane][d0 * 4 + 2] * a1) * linv;
                    float e3 = (oacc[t][h][d0][3] * a0 + lds_o[t][h][lane][d0 * 4 + 3] * a1) * linv;
                    uint2 st;
                    st.x = packbf(e0, e1);
                    st.y = packbf(e2, e3);
                    *(uint2*)(orow + d0 * 16 + g * 4) = st;
                }
            }
        }
    }
}

// ---------- launch ----------
extern "C" void kernel_launch(void* const* d_in, const int* in_sizes, int n_in,
                              void* d_out, int out_size, void* d_ws, size_t ws_size,
                              hipStream_t stream) {
    const float* x  = (const float*)d_in[0];
    const float* Wq = (const float*)d_in[1];
    const float* Wk = (const float*)d_in[2];
    const float* Wv = (const float*)d_in[3];
    const float* Wo = (const float*)d_in[4];

    char* ws = (char*)d_ws;
    // workspace layout (bytes)
    unsigned short* xb    = (unsigned short*)(ws + 0);         //  8 MB  x bf16 [8192][512]
    unsigned short* Wqb   = (unsigned short*)(ws + 8388608);   // 512 KB
    unsigned short* Wkb   = (unsigned short*)(ws + 8912896);
    unsigned short* Wvb   = (unsigned short*)(ws + 9437184);
    unsigned short* Wob   = (unsigned short*)(ws + 9961472);
    unsigned short* Qh    = (unsigned short*)(ws + 10485760);  //  8 MB [B][H][T][D]
    unsigned short* Kh    = (unsigned short*)(ws + 18874368);  //  8 MB
    unsigned short* Vt    = (unsigned short*)(ws + 27262976);  //  8 MB [B][H][D][T'] permuted
    unsigned short* attnb = (unsigned short*)(ws + 35651584);  //  8 MB [8192][512]

    const int nX = M_DIM * C_DIM;      // 4194304
    const int nW = C_DIM * C_DIM;      // 262144

    cvt_kernel<<<nX / 4 / 256, 256, 0, stream>>>(x, xb, nX);
    cvt_kernel<<<nW / 4 / 256, 256, 0, stream>>>(Wq, Wqb, nW);
    cvt_kernel<<<nW / 4 / 256, 256, 0, stream>>>(Wk, Wkb, nW);
    cvt_kernel<<<nW / 4 / 256, 256, 0, stream>>>(Wv, Wvb, nW);
    cvt_kernel<<<nW / 4 / 256, 256, 0, stream>>>(Wo, Wob, nW);

    dim3 ggrid(M_DIM / 128, C_DIM / 64);
    gemm_bt<0><<<ggrid, 256, 0, stream>>>(xb, Wqb, Qh);
    gemm_bt<0><<<ggrid, 256, 0, stream>>>(xb, Wkb, Kh);
    gemm_bt<2><<<ggrid, 256, 0, stream>>>(xb, Wvb, Vt);

    attn_kernel<<<B_DIM * H_DIM * (T_DIM / 64), 128, 0, stream>>>(Qh, Kh, Vt, attnb);

    gemm_bt<3><<<ggrid, 256, 0, stream>>>(attnb, Wob, d_out);
}